// Round 3
// baseline (4419.744 us; speedup 1.0000x reference)
//
#include <hip/hip_runtime.h>
#include <math.h>

// clDice loss via register-resident temporal cascade.
// All 10 soft_skel iterations run as a systolic pipeline of erode stages,
// swept top->bottom. Per lane: 4 columns (float4), per stage a 3-row rolling
// register window. No LDS, no barriers; horizontal halo via DPP wave shifts
// (VALU pipe, ~4cyc) instead of ds_permute (~35cyc) -- the R2 bottleneck.
//
// Geometry: wave covers 256 cols (lane*4 + 232*s - 12), owns 232 [s*232,..).
// 5 col-strips x 8 row-strips(128 rows, 11-row warmup/drain) x 64 jobs
// (= 2 tensors x 16 batch x 2 ch) = 2560 waves, one wave per 64-thread block.

#define HH 1024
#define WW 1024
#define OWN_W 232
#define VROWS 128
#define NMACRO 51   // 153 steps = 128 + 11 warmup + 12 drain + pad to x3

#define MOD3(x) ((((x) % 3) + 3) % 3)

__device__ __forceinline__ float4 f4s(float v) { float4 r; r.x = v; r.y = v; r.z = v; r.w = v; return r; }
__device__ __forceinline__ float sigm(float x) { return __builtin_amdgcn_rcpf(1.0f + __expf(-x)); }
__device__ __forceinline__ float min5(float a, float b, float c, float d, float e) {
    return fminf(fminf(fminf(a, b), fminf(c, d)), e);
}
__device__ __forceinline__ float max3(float a, float b, float c) {
    return fmaxf(fmaxf(a, b), c);
}

// lane i <- lane i-1 across the full wave (== __shfl_up(x,1,64)); lane 0 keeps own.
__device__ __forceinline__ float dpp_up1(float x) {
    int i = __builtin_bit_cast(int, x);
    int r = __builtin_amdgcn_update_dpp(i, i, 0x138, 0xf, 0xf, false);  // wave_shr:1
    return __builtin_bit_cast(float, r);
}
// lane i <- lane i+1 across the full wave (== __shfl_down(x,1,64)); lane 63 keeps own.
__device__ __forceinline__ float dpp_dn1(float x) {
    int i = __builtin_bit_cast(int, x);
    int r = __builtin_amdgcn_update_dpp(i, i, 0x130, 0xf, 0xf, false);  // wave_shl:1
    return __builtin_bit_cast(float, r);
}

__global__ __launch_bounds__(64, 4)
void skel_kernel(const float* __restrict__ logits,
                 const float* __restrict__ targets,
                 float* __restrict__ sums)
{
    const int lane = threadIdx.x & 63;
    const int gwid = blockIdx.x;         // one wave per block
    const int job  = gwid / 40;          // 0..63
    const int rem  = gwid - job * 40;
    const int s    = rem % 5;            // col strip
    const int v    = rem / 5;            // row strip
    const int tensor = job >> 5;         // 0: skel(pred), 1: skel(target)
    const int plane  = job & 31;
    const size_t planeOff = (size_t)plane * (HH * WW);
    const float* __restrict__ src  = tensor ? targets : logits;   // skel source
    const float* __restrict__ osrc = tensor ? logits  : targets;  // multiplied tensor
    const bool sEdge = (s == 0) || (s == 4);

    const int colBase = OWN_W * s - 12 + lane * 4;
    const bool colOOB = (colBase < 0) || (colBase > WW - 4);      // whole-lane by construction
    const int colC = colBase < 0 ? 0 : (colBase > WW - 4 ? WW - 4 : colBase);
    const int y0 = v * VROWS;
    const int rBase = y0 - 11;

    const int ownHi = (OWN_W * (s + 1) < WW) ? OWN_W * (s + 1) : WW;
    const bool ownedLane = (colBase >= OWN_W * s) && (colBase < ownHi);

    // E[k][slot]: stage-k erode output, 3-row rolling window. Row y lives at
    // slot (y - rBase) mod 3 (stage-independent). E[0] = source image window.
    float4 E[11][3];
#pragma unroll
    for (int k = 0; k < 11; ++k)
#pragma unroll
        for (int j = 0; j < 3; ++j) E[k][j] = f4s(INFINITY);

    // shift-register ring of 'other' rows; at macro m, slot j holds row
    // (y0 - 23 + 3m + j). Stage k, phase p reads slot 10+p-k (row = dilate row).
    float4 oring[15];
#pragma unroll
    for (int j = 0; j < 15; ++j) oring[j] = f4s(0.f);

    float4 sumS = f4s(0.f), sumP = f4s(0.f);

    auto loadImg = [&](int row) -> float4 {
        float4 x;
        if ((unsigned)row < HH) {
            const float* p = src + planeOff + (size_t)row * WW + colC;
            x = *(const float4*)p;
            if (!tensor) { x.x = sigm(x.x); x.y = sigm(x.y); x.z = sigm(x.z); x.w = sigm(x.w); }
            if (sEdge && colOOB) x = f4s(INFINITY);
        } else {
            x = f4s(INFINITY);   // out-of-image rows: erode identity
        }
        return x;
    };
    auto loadOther = [&](int row) -> float4 {
        int rc = row < 0 ? 0 : (row > HH - 1 ? HH - 1 : row);
        const float* p = osrc + planeOff + (size_t)rc * WW + colC;
        float4 x = *(const float4*)p;
        if (tensor) { x.x = sigm(x.x); x.y = sigm(x.y); x.z = sigm(x.z); x.w = sigm(x.w); }
        return x;
    };

    float4 nextImg = loadImg(rBase);   // prefetch row for t=0

#pragma unroll 1
    for (int m = 0; m < NMACRO; ++m) {
        // ring shift + 3 new 'other' rows (consumed >=4 steps later)
#pragma unroll
        for (int j = 0; j < 12; ++j) oring[j] = oring[j + 3];
#pragma unroll
        for (int j = 0; j < 3; ++j) oring[12 + j] = loadOther(rBase + 3 * m + j);

#pragma unroll
        for (int p = 0; p < 3; ++p) {
            const int r = rBase + 3 * m + p;     // img row fed this step
            const float4 img = nextImg;
            nextImg = loadImg(r + 1);            // prefetch next step's row

            // ---------- Pass D: dilate stage k at row yd = r-k-2 (pre-update windows) ----------
#pragma unroll
            for (int k = 1; k <= 10; ++k) {
                const int yd = r - k - 2;
                if (yd >= y0 && yd < y0 + VROWS) {      // wave-uniform ownership guard
                    const float4 a = E[k][MOD3(p - k)];       // row yd-1
                    const float4 b = E[k][MOD3(p - k + 1)];   // row yd
                    const float4 c = E[k][MOD3(p - k + 2)];   // row yd+1
                    float4 vm;
                    if (yd == 0) {                // image top: exclude row -1
                        vm.x = fmaxf(b.x, c.x); vm.y = fmaxf(b.y, c.y);
                        vm.z = fmaxf(b.z, c.z); vm.w = fmaxf(b.w, c.w);
                    } else if (yd == HH - 1) {    // image bottom: exclude row 1024
                        vm.x = fmaxf(a.x, b.x); vm.y = fmaxf(a.y, b.y);
                        vm.z = fmaxf(a.z, b.z); vm.w = fmaxf(a.w, b.w);
                    } else {
                        vm.x = max3(a.x, b.x, c.x); vm.y = max3(a.y, b.y, c.y);
                        vm.z = max3(a.z, b.z, c.z); vm.w = max3(a.w, b.w, c.w);
                    }
                    if (sEdge) { if (colOOB) vm = f4s(-INFINITY); }  // col truncation at image edge
                    const float vl = dpp_up1(vm.w);
                    const float vr = dpp_dn1(vm.x);
                    float4 h;
                    h.x = max3(vl,   vm.x, vm.y);
                    h.y = max3(vm.x, vm.y, vm.z);
                    h.z = max3(vm.y, vm.z, vm.w);
                    h.w = max3(vm.z, vm.w, vr);
                    const float4 io = E[k - 1][MOD3(p - k + 1)];  // img_k at row yd
                    float4 ct;
                    ct.x = fmaxf(io.x - h.x, 0.f);
                    ct.y = fmaxf(io.y - h.y, 0.f);
                    ct.z = fmaxf(io.z - h.z, 0.f);
                    ct.w = fmaxf(io.w - h.w, 0.f);
                    const float4 ot = oring[10 + p - k];
                    sumS.x += ct.x; sumS.y += ct.y; sumS.z += ct.z; sumS.w += ct.w;
                    sumP.x = fmaf(ot.x, ct.x, sumP.x);
                    sumP.y = fmaf(ot.y, ct.y, sumP.y);
                    sumP.z = fmaf(ot.z, ct.z, sumP.z);
                    sumP.w = fmaf(ot.w, ct.w, sumP.w);
                }
            }

            // ---------- Pass E: erode cascade, stage k emits row r-k ----------
            E[0][MOD3(p)] = img;
            float4 np_ = img;    // new row of stage k-1 (row r-k+1 when at stage k)
#pragma unroll
            for (int k = 1; k <= 10; ++k) {
                const float4 A = E[k - 1][MOD3(p - k + 2)];  // row r-k-1 (up)
                const float4 B = E[k - 1][MOD3(p - k)];      // row r-k   (center)
                const float4 C = np_;                        // row r-k+1 (down)
                const float bl = dpp_up1(B.w);
                const float br = dpp_dn1(B.x);
                float4 ne;
                ne.x = min5(A.x, C.x, bl,  B.y, B.x);
                ne.y = min5(A.y, C.y, B.x, B.z, B.y);
                ne.z = min5(A.z, C.z, B.y, B.w, B.z);
                ne.w = min5(A.w, C.w, B.z, br,  B.w);
                const int yN = r - k;
                if ((unsigned)yN >= HH) {        // out-of-image rows stay +inf
                    ne = f4s(INFINITY);
                } else if (sEdge) {
                    if (colOOB) ne = f4s(INFINITY);  // out-of-image cols stay +inf
                }
                E[k][MOD3(p - k)] = ne;
                np_ = ne;
            }
        }
    }

    // ---------- reduce: mask unowned lanes, wave-reduce, 2 atomics ----------
    if (!ownedLane) { sumS = f4s(0.f); sumP = f4s(0.f); }
    float aS = sumS.x + sumS.y + sumS.z + sumS.w;
    float aP = sumP.x + sumP.y + sumP.z + sumP.w;
#pragma unroll
    for (int off = 32; off > 0; off >>= 1) {
        aS += __shfl_down(aS, off, 64);
        aP += __shfl_down(aP, off, 64);
    }
    if (lane == 0) {
        const int base = plane * 4 + tensor * 2;
        atomicAdd(&sums[base],     aS);   // sum(skel)
        atomicAdd(&sums[base + 1], aP);   // sum(skel * other)
    }
}

__global__ void finalize_kernel(const float* __restrict__ s4, float* __restrict__ out)
{
    __shared__ float cl[32];
    int p = threadIdx.x;
    if (p < 32) {
        const float* s = s4 + p * 4;
        float tprec = s[1] / (s[0] + 1e-6f);
        float tsens = s[3] / (s[2] + 1e-6f);
        cl[p] = 2.f * tprec * tsens / (tprec + tsens + 1e-6f);
    }
    __syncthreads();
    if (p == 0) {
        float a = 0.f, vch = 0.f;
        for (int b = 0; b < 16; ++b) { a += cl[b * 2]; vch += cl[b * 2 + 1]; }
        out[0] = 1.f - 0.5f * (a / 16.f + vch / 16.f);
    }
}

extern "C" void kernel_launch(void* const* d_in, const int* in_sizes, int n_in,
                              void* d_out, int out_size, void* d_ws, size_t ws_size,
                              hipStream_t stream)
{
    const float* logits  = (const float*)d_in[0];
    const float* targets = (const float*)d_in[1];
    float* out  = (float*)d_out;
    float* sums = (float*)d_ws;

    hipMemsetAsync(d_ws, 0, 32 * 4 * sizeof(float), stream);

    // 2560 waves = 5 col-strips x 8 row-strips x 64 jobs; 1 wave per block
    skel_kernel<<<2560, 64, 0, stream>>>(logits, targets, sums);
    finalize_kernel<<<1, 64, 0, stream>>>(sums, out);
}

// Round 4
// 990.884 us; speedup vs baseline: 4.4604x; 4.4604x over previous
//
#include <hip/hip_runtime.h>
#include <math.h>

// clDice loss via register-resident temporal cascade.
// All 10 soft_skel iterations run as a systolic pipeline of erode stages,
// swept top->bottom. Per lane: 4 columns (float4), per stage a 3-row rolling
// register window. No LDS, no barriers; horizontal halo via DPP wave shifts
// (VALU pipe, ~4cyc) instead of ds_permute (~35cyc).
//
// R3 post-mortem: 64-thread blocks + __launch_bounds__(64,4) made the
// compiler allocate only 64 VGPRs -> full pipeline state spilled to scratch
// (11.6 GB HBM traffic, 4.3 ms). Geometry reverted to R2's 256-thread
// blocks / (256,2) which compiles spill-free at 128 VGPRs.
//
// Geometry: wave covers 256 cols (lane*4 + 232*s - 12), owns 232 [s*232,..).
// 5 col-strips x 8 row-strips(128 rows, 11-row warmup/drain) x 64 jobs
// (= 2 tensors x 16 batch x 2 ch) = 2560 waves, 640 blocks of 256.

#define HH 1024
#define WW 1024
#define OWN_W 232
#define VROWS 128
#define NMACRO 51   // 153 steps = 128 + 11 warmup + 12 drain + pad to x3

#define MOD3(x) ((((x) % 3) + 3) % 3)

__device__ __forceinline__ float4 f4s(float v) { float4 r; r.x = v; r.y = v; r.z = v; r.w = v; return r; }
__device__ __forceinline__ float sigm(float x) { return __builtin_amdgcn_rcpf(1.0f + __expf(-x)); }
__device__ __forceinline__ float min5(float a, float b, float c, float d, float e) {
    return fminf(fminf(fminf(a, b), fminf(c, d)), e);
}
__device__ __forceinline__ float max3(float a, float b, float c) {
    return fmaxf(fmaxf(a, b), c);
}

// lane i <- lane i-1 across the full wave (== __shfl_up(x,1,64)); lane 0 keeps own.
__device__ __forceinline__ float dpp_up1(float x) {
    int i = __builtin_bit_cast(int, x);
    int r = __builtin_amdgcn_update_dpp(i, i, 0x138, 0xf, 0xf, false);  // wave_shr:1
    return __builtin_bit_cast(float, r);
}
// lane i <- lane i+1 across the full wave (== __shfl_down(x,1,64)); lane 63 keeps own.
__device__ __forceinline__ float dpp_dn1(float x) {
    int i = __builtin_bit_cast(int, x);
    int r = __builtin_amdgcn_update_dpp(i, i, 0x130, 0xf, 0xf, false);  // wave_shl:1
    return __builtin_bit_cast(float, r);
}

__global__ __launch_bounds__(256, 2)
void skel_kernel(const float* __restrict__ logits,
                 const float* __restrict__ targets,
                 float* __restrict__ sums)
{
    const int lane = threadIdx.x & 63;
    const int gwid = __builtin_amdgcn_readfirstlane(blockIdx.x * 4 + (threadIdx.x >> 6));
    const int job  = gwid / 40;          // 0..63
    const int rem  = gwid - job * 40;
    const int s    = rem % 5;            // col strip
    const int v    = rem / 5;            // row strip
    const int tensor = job >> 5;         // 0: skel(pred), 1: skel(target)
    const int plane  = job & 31;
    const size_t planeOff = (size_t)plane * (HH * WW);
    const float* __restrict__ src  = tensor ? targets : logits;   // skel source
    const float* __restrict__ osrc = tensor ? logits  : targets;  // multiplied tensor
    const bool sEdge = (s == 0) || (s == 4);

    const int colBase = OWN_W * s - 12 + lane * 4;
    const bool colOOB = (colBase < 0) || (colBase > WW - 4);      // whole-lane by construction
    const int colC = colBase < 0 ? 0 : (colBase > WW - 4 ? WW - 4 : colBase);
    const int y0 = v * VROWS;
    const int rBase = y0 - 11;

    const int ownHi = (OWN_W * (s + 1) < WW) ? OWN_W * (s + 1) : WW;
    const bool ownedLane = (colBase >= OWN_W * s) && (colBase < ownHi);

    // E[k][slot]: stage-k erode output, 3-row rolling window. Row y lives at
    // slot (y - rBase) mod 3 (stage-independent). E[0] = source image window.
    float4 E[11][3];
#pragma unroll
    for (int k = 0; k < 11; ++k)
#pragma unroll
        for (int j = 0; j < 3; ++j) E[k][j] = f4s(INFINITY);

    // shift-register ring of 'other' rows; at macro m, slot j holds row
    // (y0 - 23 + 3m + j). Stage k, phase p reads slot 10+p-k (row = dilate row).
    float4 oring[15];
#pragma unroll
    for (int j = 0; j < 15; ++j) oring[j] = f4s(0.f);

    float4 sumS = f4s(0.f), sumP = f4s(0.f);

    auto loadImg = [&](int row) -> float4 {
        float4 x;
        if ((unsigned)row < HH) {
            const float* p = src + planeOff + (size_t)row * WW + colC;
            x = *(const float4*)p;
            if (!tensor) { x.x = sigm(x.x); x.y = sigm(x.y); x.z = sigm(x.z); x.w = sigm(x.w); }
            if (sEdge && colOOB) x = f4s(INFINITY);
        } else {
            x = f4s(INFINITY);   // out-of-image rows: erode identity
        }
        return x;
    };
    auto loadOther = [&](int row) -> float4 {
        int rc = row < 0 ? 0 : (row > HH - 1 ? HH - 1 : row);
        const float* p = osrc + planeOff + (size_t)rc * WW + colC;
        float4 x = *(const float4*)p;
        if (tensor) { x.x = sigm(x.x); x.y = sigm(x.y); x.z = sigm(x.z); x.w = sigm(x.w); }
        return x;
    };

    float4 nextImg = loadImg(rBase);   // prefetch row for t=0

#pragma unroll 1
    for (int m = 0; m < NMACRO; ++m) {
        // ring shift + 3 new 'other' rows (consumed >=4 steps later)
#pragma unroll
        for (int j = 0; j < 12; ++j) oring[j] = oring[j + 3];
#pragma unroll
        for (int j = 0; j < 3; ++j) oring[12 + j] = loadOther(rBase + 3 * m + j);

#pragma unroll
        for (int p = 0; p < 3; ++p) {
            const int r = rBase + 3 * m + p;     // img row fed this step
            const float4 img = nextImg;
            nextImg = loadImg(r + 1);            // prefetch next step's row

            // ---------- Pass D: dilate stage k at row yd = r-k-2 (pre-update windows) ----------
#pragma unroll
            for (int k = 1; k <= 10; ++k) {
                const int yd = r - k - 2;
                if (yd >= y0 && yd < y0 + VROWS) {      // wave-uniform ownership guard
                    const float4 a = E[k][MOD3(p - k)];       // row yd-1
                    const float4 b = E[k][MOD3(p - k + 1)];   // row yd
                    const float4 c = E[k][MOD3(p - k + 2)];   // row yd+1
                    float4 vm;
                    if (yd == 0) {                // image top: exclude row -1
                        vm.x = fmaxf(b.x, c.x); vm.y = fmaxf(b.y, c.y);
                        vm.z = fmaxf(b.z, c.z); vm.w = fmaxf(b.w, c.w);
                    } else if (yd == HH - 1) {    // image bottom: exclude row 1024
                        vm.x = fmaxf(a.x, b.x); vm.y = fmaxf(a.y, b.y);
                        vm.z = fmaxf(a.z, b.z); vm.w = fmaxf(a.w, b.w);
                    } else {
                        vm.x = max3(a.x, b.x, c.x); vm.y = max3(a.y, b.y, c.y);
                        vm.z = max3(a.z, b.z, c.z); vm.w = max3(a.w, b.w, c.w);
                    }
                    if (sEdge) { if (colOOB) vm = f4s(-INFINITY); }  // col truncation at image edge
                    const float vl = dpp_up1(vm.w);
                    const float vr = dpp_dn1(vm.x);
                    float4 h;
                    h.x = max3(vl,   vm.x, vm.y);
                    h.y = max3(vm.x, vm.y, vm.z);
                    h.z = max3(vm.y, vm.z, vm.w);
                    h.w = max3(vm.z, vm.w, vr);
                    const float4 io = E[k - 1][MOD3(p - k + 1)];  // img_k at row yd
                    float4 ct;
                    ct.x = fmaxf(io.x - h.x, 0.f);
                    ct.y = fmaxf(io.y - h.y, 0.f);
                    ct.z = fmaxf(io.z - h.z, 0.f);
                    ct.w = fmaxf(io.w - h.w, 0.f);
                    const float4 ot = oring[10 + p - k];
                    sumS.x += ct.x; sumS.y += ct.y; sumS.z += ct.z; sumS.w += ct.w;
                    sumP.x = fmaf(ot.x, ct.x, sumP.x);
                    sumP.y = fmaf(ot.y, ct.y, sumP.y);
                    sumP.z = fmaf(ot.z, ct.z, sumP.z);
                    sumP.w = fmaf(ot.w, ct.w, sumP.w);
                }
            }

            // ---------- Pass E: erode cascade, stage k emits row r-k ----------
            E[0][MOD3(p)] = img;
            float4 np_ = img;    // new row of stage k-1 (row r-k+1 when at stage k)
#pragma unroll
            for (int k = 1; k <= 10; ++k) {
                const float4 A = E[k - 1][MOD3(p - k + 2)];  // row r-k-1 (up)
                const float4 B = E[k - 1][MOD3(p - k)];      // row r-k   (center)
                const float4 C = np_;                        // row r-k+1 (down)
                const float bl = dpp_up1(B.w);
                const float br = dpp_dn1(B.x);
                float4 ne;
                ne.x = min5(A.x, C.x, bl,  B.y, B.x);
                ne.y = min5(A.y, C.y, B.x, B.z, B.y);
                ne.z = min5(A.z, C.z, B.y, B.w, B.z);
                ne.w = min5(A.w, C.w, B.z, br,  B.w);
                const int yN = r - k;
                if ((unsigned)yN >= HH) {        // out-of-image rows stay +inf
                    ne = f4s(INFINITY);
                } else if (sEdge) {
                    if (colOOB) ne = f4s(INFINITY);  // out-of-image cols stay +inf
                }
                E[k][MOD3(p - k)] = ne;
                np_ = ne;
            }
        }
    }

    // ---------- reduce: mask unowned lanes, wave-reduce, 2 atomics ----------
    if (!ownedLane) { sumS = f4s(0.f); sumP = f4s(0.f); }
    float aS = sumS.x + sumS.y + sumS.z + sumS.w;
    float aP = sumP.x + sumP.y + sumP.z + sumP.w;
#pragma unroll
    for (int off = 32; off > 0; off >>= 1) {
        aS += __shfl_down(aS, off, 64);
        aP += __shfl_down(aP, off, 64);
    }
    if (lane == 0) {
        const int base = plane * 4 + tensor * 2;
        atomicAdd(&sums[base],     aS);   // sum(skel)
        atomicAdd(&sums[base + 1], aP);   // sum(skel * other)
    }
}

__global__ void finalize_kernel(const float* __restrict__ s4, float* __restrict__ out)
{
    __shared__ float cl[32];
    int p = threadIdx.x;
    if (p < 32) {
        const float* s = s4 + p * 4;
        float tprec = s[1] / (s[0] + 1e-6f);
        float tsens = s[3] / (s[2] + 1e-6f);
        cl[p] = 2.f * tprec * tsens / (tprec + tsens + 1e-6f);
    }
    __syncthreads();
    if (p == 0) {
        float a = 0.f, vch = 0.f;
        for (int b = 0; b < 16; ++b) { a += cl[b * 2]; vch += cl[b * 2 + 1]; }
        out[0] = 1.f - 0.5f * (a / 16.f + vch / 16.f);
    }
}

extern "C" void kernel_launch(void* const* d_in, const int* in_sizes, int n_in,
                              void* d_out, int out_size, void* d_ws, size_t ws_size,
                              hipStream_t stream)
{
    const float* logits  = (const float*)d_in[0];
    const float* targets = (const float*)d_in[1];
    float* out  = (float*)d_out;
    float* sums = (float*)d_ws;

    hipMemsetAsync(d_ws, 0, 32 * 4 * sizeof(float), stream);

    // 2560 waves = 5 col-strips x 8 row-strips x 64 jobs; 4 waves per block
    skel_kernel<<<640, 256, 0, stream>>>(logits, targets, sums);
    finalize_kernel<<<1, 64, 0, stream>>>(sums, out);
}

// Round 5
// 780.512 us; speedup vs baseline: 5.6626x; 1.2695x over previous
//
#include <hip/hip_runtime.h>
#include <math.h>

// clDice loss via register-resident temporal cascade (float2 lanes).
// All 10 soft_skel iterations run as a systolic pipeline of erode stages,
// swept top->bottom. Per lane: 2 columns (float2), per stage a 3-row rolling
// register window. No LDS, no barriers; horizontal halo via DPP wave shifts.
// min/max via inline asm (v_min_f32/v_max_f32) to kill IEEE canonicalize
// padding around fminf/fmaxf (R4: ~2x VALU inst bloat).
//
// Geometry: wave covers 128 cols (lane*2 + 104*s - 12), owns 104 [104s,..).
// 10 col-strips x 8 row-strips(128 rows, 11-row warmup/drain) x 64 jobs
// (= 2 tensors x 16 batch x 2 ch) = 5120 waves, 1280 blocks of 256
// = exactly 5 blocks/CU (4 resident at 128-VGPR cap) -- no ragged tail.

#define HH 1024
#define WW 1024
#define OWN_W 104
#define VROWS 128
#define NMACRO 51   // 153 steps = 128 + 11 warmup + 12 drain + pad to x3

#define MOD3(x) ((((x) % 3) + 3) % 3)

__device__ __forceinline__ float2 f2s(float v) { float2 r; r.x = v; r.y = v; return r; }
__device__ __forceinline__ float sigm(float x) { return __builtin_amdgcn_rcpf(1.0f + __expf(-x)); }

// single-instruction min/max: bypasses IEEE-mode canonicalization
__device__ __forceinline__ float vmin(float a, float b) {
    float d; asm("v_min_f32 %0, %1, %2" : "=v"(d) : "v"(a), "v"(b)); return d;
}
__device__ __forceinline__ float vmax(float a, float b) {
    float d; asm("v_max_f32 %0, %1, %2" : "=v"(d) : "v"(a), "v"(b)); return d;
}
__device__ __forceinline__ float min5(float a, float b, float c, float d, float e) {
    return vmin(vmin(vmin(a, b), vmin(c, d)), e);
}
__device__ __forceinline__ float max3(float a, float b, float c) {
    return vmax(vmax(a, b), c);
}

// lane i <- lane i-1 across the full wave (== __shfl_up(x,1,64)); lane 0 keeps own.
__device__ __forceinline__ float dpp_up1(float x) {
    int i = __builtin_bit_cast(int, x);
    int r = __builtin_amdgcn_update_dpp(i, i, 0x138, 0xf, 0xf, false);  // wave_shr:1
    return __builtin_bit_cast(float, r);
}
// lane i <- lane i+1 across the full wave (== __shfl_down(x,1,64)); lane 63 keeps own.
__device__ __forceinline__ float dpp_dn1(float x) {
    int i = __builtin_bit_cast(int, x);
    int r = __builtin_amdgcn_update_dpp(i, i, 0x130, 0xf, 0xf, false);  // wave_shl:1
    return __builtin_bit_cast(float, r);
}

__global__ __launch_bounds__(256, 4)
void skel_kernel(const float* __restrict__ logits,
                 const float* __restrict__ targets,
                 float* __restrict__ sums)
{
    const int lane = threadIdx.x & 63;
    const int gwid = __builtin_amdgcn_readfirstlane(blockIdx.x * 4 + (threadIdx.x >> 6));
    const int job  = gwid / 80;          // 0..63
    const int rem  = gwid - job * 80;
    const int s    = rem % 10;           // col strip
    const int v    = rem / 10;           // row strip
    const int tensor = job >> 5;         // 0: skel(pred), 1: skel(target)
    const int plane  = job & 31;
    const size_t planeOff = (size_t)plane * (HH * WW);
    const float* __restrict__ src  = tensor ? targets : logits;   // skel source
    const float* __restrict__ osrc = tensor ? logits  : targets;  // multiplied tensor
    const bool sEdge = (s == 0) || (s == 9);

    const int colBase = OWN_W * s - 12 + lane * 2;
    const bool colOOB = (colBase < 0) || (colBase > WW - 2);      // whole-lane (even boundaries)
    const int colC = colBase < 0 ? 0 : (colBase > WW - 2 ? WW - 2 : colBase);
    const int y0 = v * VROWS;
    const int rBase = y0 - 11;

    const int ownHi = (OWN_W * (s + 1) < WW) ? OWN_W * (s + 1) : WW;
    const bool ownedLane = (colBase >= OWN_W * s) && (colBase < ownHi);

    // E[k][slot]: stage-k erode output, 3-row rolling window. Row y lives at
    // slot (y - rBase) mod 3 (stage-independent). E[0] = source image window.
    float2 E[11][3];
#pragma unroll
    for (int k = 0; k < 11; ++k)
#pragma unroll
        for (int j = 0; j < 3; ++j) E[k][j] = f2s(INFINITY);

    // shift-register ring of 'other' rows; at macro m, slot j holds row
    // (y0 - 23 + 3m + j). Stage k, phase p reads slot 10+p-k (row = dilate row).
    float2 oring[15];
#pragma unroll
    for (int j = 0; j < 15; ++j) oring[j] = f2s(0.f);

    float2 sumS = f2s(0.f), sumP = f2s(0.f);

    auto loadImg = [&](int row) -> float2 {
        float2 x;
        if ((unsigned)row < HH) {
            const float* p = src + planeOff + (size_t)row * WW + colC;
            x = *(const float2*)p;
            if (!tensor) { x.x = sigm(x.x); x.y = sigm(x.y); }
            if (sEdge && colOOB) x = f2s(INFINITY);
        } else {
            x = f2s(INFINITY);   // out-of-image rows: erode identity
        }
        return x;
    };
    auto loadOther = [&](int row) -> float2 {
        int rc = row < 0 ? 0 : (row > HH - 1 ? HH - 1 : row);
        const float* p = osrc + planeOff + (size_t)rc * WW + colC;
        float2 x = *(const float2*)p;
        if (tensor) { x.x = sigm(x.x); x.y = sigm(x.y); }
        return x;
    };

    float2 nextImg = loadImg(rBase);   // prefetch row for t=0

#pragma unroll 1
    for (int m = 0; m < NMACRO; ++m) {
        // ring shift + 3 new 'other' rows (consumed >=4 steps later)
#pragma unroll
        for (int j = 0; j < 12; ++j) oring[j] = oring[j + 3];
#pragma unroll
        for (int j = 0; j < 3; ++j) oring[12 + j] = loadOther(rBase + 3 * m + j);

#pragma unroll
        for (int p = 0; p < 3; ++p) {
            const int r = rBase + 3 * m + p;     // img row fed this step
            const float2 img = nextImg;
            nextImg = loadImg(r + 1);            // prefetch next step's row

            // ---------- Pass D: dilate stage k at row yd = r-k-2 (pre-update windows) ----------
#pragma unroll
            for (int k = 1; k <= 10; ++k) {
                const int yd = r - k - 2;
                if (yd >= y0 && yd < y0 + VROWS) {      // wave-uniform ownership guard
                    const float2 a = E[k][MOD3(p - k)];       // row yd-1
                    const float2 b = E[k][MOD3(p - k + 1)];   // row yd
                    const float2 c = E[k][MOD3(p - k + 2)];   // row yd+1
                    float2 vm;
                    if (yd == 0) {                // image top: exclude row -1
                        vm.x = vmax(b.x, c.x); vm.y = vmax(b.y, c.y);
                    } else if (yd == HH - 1) {    // image bottom: exclude row 1024
                        vm.x = vmax(a.x, b.x); vm.y = vmax(a.y, b.y);
                    } else {
                        vm.x = max3(a.x, b.x, c.x); vm.y = max3(a.y, b.y, c.y);
                    }
                    if (sEdge) { if (colOOB) vm = f2s(-INFINITY); }  // col truncation at image edge
                    const float vl = dpp_up1(vm.y);
                    const float vr = dpp_dn1(vm.x);
                    float2 h;
                    h.x = max3(vl,   vm.x, vm.y);
                    h.y = max3(vm.x, vm.y, vr);
                    const float2 io = E[k - 1][MOD3(p - k + 1)];  // img_k at row yd
                    float2 ct;
                    ct.x = fmaxf(io.x - h.x, 0.f);
                    ct.y = fmaxf(io.y - h.y, 0.f);
                    const float2 ot = oring[10 + p - k];
                    sumS.x += ct.x; sumS.y += ct.y;
                    sumP.x = fmaf(ot.x, ct.x, sumP.x);
                    sumP.y = fmaf(ot.y, ct.y, sumP.y);
                }
            }

            // ---------- Pass E: erode cascade, stage k emits row r-k ----------
            E[0][MOD3(p)] = img;
            float2 np_ = img;    // new row of stage k-1 (row r-k+1 when at stage k)
#pragma unroll
            for (int k = 1; k <= 10; ++k) {
                const float2 A = E[k - 1][MOD3(p - k + 2)];  // row r-k-1 (up)
                const float2 B = E[k - 1][MOD3(p - k)];      // row r-k   (center)
                const float2 C = np_;                        // row r-k+1 (down)
                const float bl = dpp_up1(B.y);
                const float br = dpp_dn1(B.x);
                float2 ne;
                ne.x = min5(A.x, C.x, bl,  B.y, B.x);
                ne.y = min5(A.y, C.y, B.x, br,  B.y);
                const int yN = r - k;
                if ((unsigned)yN >= HH) {        // out-of-image rows stay +inf
                    ne = f2s(INFINITY);
                } else if (sEdge) {
                    if (colOOB) ne = f2s(INFINITY);  // out-of-image cols stay +inf
                }
                E[k][MOD3(p - k)] = ne;
                np_ = ne;
            }
        }
    }

    // ---------- reduce: mask unowned lanes, wave-reduce, 2 atomics ----------
    if (!ownedLane) { sumS = f2s(0.f); sumP = f2s(0.f); }
    float aS = sumS.x + sumS.y;
    float aP = sumP.x + sumP.y;
#pragma unroll
    for (int off = 32; off > 0; off >>= 1) {
        aS += __shfl_down(aS, off, 64);
        aP += __shfl_down(aP, off, 64);
    }
    if (lane == 0) {
        const int base = plane * 4 + tensor * 2;
        atomicAdd(&sums[base],     aS);   // sum(skel)
        atomicAdd(&sums[base + 1], aP);   // sum(skel * other)
    }
}

__global__ void finalize_kernel(const float* __restrict__ s4, float* __restrict__ out)
{
    __shared__ float cl[32];
    int p = threadIdx.x;
    if (p < 32) {
        const float* s = s4 + p * 4;
        float tprec = s[1] / (s[0] + 1e-6f);
        float tsens = s[3] / (s[2] + 1e-6f);
        cl[p] = 2.f * tprec * tsens / (tprec + tsens + 1e-6f);
    }
    __syncthreads();
    if (p == 0) {
        float a = 0.f, vch = 0.f;
        for (int b = 0; b < 16; ++b) { a += cl[b * 2]; vch += cl[b * 2 + 1]; }
        out[0] = 1.f - 0.5f * (a / 16.f + vch / 16.f);
    }
}

extern "C" void kernel_launch(void* const* d_in, const int* in_sizes, int n_in,
                              void* d_out, int out_size, void* d_ws, size_t ws_size,
                              hipStream_t stream)
{
    const float* logits  = (const float*)d_in[0];
    const float* targets = (const float*)d_in[1];
    float* out  = (float*)d_out;
    float* sums = (float*)d_ws;

    hipMemsetAsync(d_ws, 0, 32 * 4 * sizeof(float), stream);

    // 5120 waves = 10 col-strips x 8 row-strips x 64 jobs; 4 waves per block
    skel_kernel<<<1280, 256, 0, stream>>>(logits, targets, sums);
    finalize_kernel<<<1, 64, 0, stream>>>(sums, out);
}

// Round 6
// 726.866 us; speedup vs baseline: 6.0806x; 1.0738x over previous
//
#include <hip/hip_runtime.h>
#include <math.h>

// clDice loss via register-resident temporal cascade (float2 lanes).
// All 10 soft_skel iterations run as a systolic pipeline of erode stages,
// swept top->bottom. Per lane: 2 columns (float2), per stage a 3-row rolling
// register window. No LDS, no barriers; horizontal halo via DPP wave shifts.
// R6: min/max trees emitted as single VOP3 v_min3_f32/v_max3_f32 (R5's
// 2-operand asm blocked the fusion -> ~2x dynamic VALU bloat).
//
// Geometry: wave covers 128 cols (lane*2 + 104*s - 12), owns 104 [104s,..).
// 10 col-strips x 8 row-strips(128 rows, 11-row warmup/drain) x 64 jobs
// (= 2 tensors x 16 batch x 2 ch) = 5120 waves, 1280 blocks of 256
// = exactly 5 blocks/CU.

#define HH 1024
#define WW 1024
#define OWN_W 104
#define VROWS 128
#define NMACRO 51   // 153 steps = 128 + 11 warmup + 12 drain + pad to x3

#define MOD3(x) ((((x) % 3) + 3) % 3)

__device__ __forceinline__ float2 f2s(float v) { float2 r; r.x = v; r.y = v; return r; }
__device__ __forceinline__ float sigm(float x) { return __builtin_amdgcn_rcpf(1.0f + __expf(-x)); }

// single-instruction VOP3 3-operand min/max (no IEEE canonicalize padding)
__device__ __forceinline__ float vmin3(float a, float b, float c) {
    float d; asm("v_min3_f32 %0, %1, %2, %3" : "=v"(d) : "v"(a), "v"(b), "v"(c)); return d;
}
__device__ __forceinline__ float vmax3(float a, float b, float c) {
    float d; asm("v_max3_f32 %0, %1, %2, %3" : "=v"(d) : "v"(a), "v"(b), "v"(c)); return d;
}
__device__ __forceinline__ float vmax(float a, float b) {
    float d; asm("v_max_f32 %0, %1, %2" : "=v"(d) : "v"(a), "v"(b)); return d;
}
__device__ __forceinline__ float relu(float x) {
    float d; asm("v_max_f32 %0, 0, %1" : "=v"(d) : "v"(x)); return d;
}
__device__ __forceinline__ float min5(float a, float b, float c, float d, float e) {
    return vmin3(vmin3(a, b, c), d, e);
}

// lane i <- lane i-1 across the full wave (== __shfl_up(x,1,64)); lane 0 keeps own.
__device__ __forceinline__ float dpp_up1(float x) {
    int i = __builtin_bit_cast(int, x);
    int r = __builtin_amdgcn_update_dpp(i, i, 0x138, 0xf, 0xf, false);  // wave_shr:1
    return __builtin_bit_cast(float, r);
}
// lane i <- lane i+1 across the full wave (== __shfl_down(x,1,64)); lane 63 keeps own.
__device__ __forceinline__ float dpp_dn1(float x) {
    int i = __builtin_bit_cast(int, x);
    int r = __builtin_amdgcn_update_dpp(i, i, 0x130, 0xf, 0xf, false);  // wave_shl:1
    return __builtin_bit_cast(float, r);
}

__global__ __launch_bounds__(256, 4)
void skel_kernel(const float* __restrict__ logits,
                 const float* __restrict__ targets,
                 float* __restrict__ sums)
{
    const int lane = threadIdx.x & 63;
    const int gwid = __builtin_amdgcn_readfirstlane(blockIdx.x * 4 + (threadIdx.x >> 6));
    const int job  = gwid / 80;          // 0..63
    const int rem  = gwid - job * 80;
    const int s    = rem % 10;           // col strip
    const int v    = rem / 10;           // row strip
    const int tensor = job >> 5;         // 0: skel(pred), 1: skel(target)
    const int plane  = job & 31;
    const size_t planeOff = (size_t)plane * (HH * WW);
    const float* __restrict__ src  = tensor ? targets : logits;   // skel source
    const float* __restrict__ osrc = tensor ? logits  : targets;  // multiplied tensor
    const bool sEdge = (s == 0) || (s == 9);

    const int colBase = OWN_W * s - 12 + lane * 2;
    const bool colOOB = (colBase < 0) || (colBase > WW - 2);      // whole-lane (even boundaries)
    const int colC = colBase < 0 ? 0 : (colBase > WW - 2 ? WW - 2 : colBase);
    const int y0 = v * VROWS;
    const int rBase = y0 - 11;

    const int ownHi = (OWN_W * (s + 1) < WW) ? OWN_W * (s + 1) : WW;
    const bool ownedLane = (colBase >= OWN_W * s) && (colBase < ownHi);

    // E[k][slot]: stage-k erode output, 3-row rolling window. Row y lives at
    // slot (y - rBase) mod 3 (stage-independent). E[0] = source image window.
    float2 E[11][3];
#pragma unroll
    for (int k = 0; k < 11; ++k)
#pragma unroll
        for (int j = 0; j < 3; ++j) E[k][j] = f2s(INFINITY);

    // shift-register ring of 'other' rows; at macro m, slot j holds row
    // (y0 - 23 + 3m + j). Stage k, phase p reads slot 10+p-k (row = dilate row).
    float2 oring[15];
#pragma unroll
    for (int j = 0; j < 15; ++j) oring[j] = f2s(0.f);

    float2 sumS = f2s(0.f), sumP = f2s(0.f);

    auto loadImg = [&](int row) -> float2 {
        float2 x;
        if ((unsigned)row < HH) {
            const float* p = src + planeOff + (size_t)row * WW + colC;
            x = *(const float2*)p;
            if (!tensor) { x.x = sigm(x.x); x.y = sigm(x.y); }
            if (sEdge && colOOB) x = f2s(INFINITY);
        } else {
            x = f2s(INFINITY);   // out-of-image rows: erode identity
        }
        return x;
    };
    auto loadOther = [&](int row) -> float2 {
        int rc = row < 0 ? 0 : (row > HH - 1 ? HH - 1 : row);
        const float* p = osrc + planeOff + (size_t)rc * WW + colC;
        float2 x = *(const float2*)p;
        if (tensor) { x.x = sigm(x.x); x.y = sigm(x.y); }
        return x;
    };

    float2 nextImg = loadImg(rBase);   // prefetch row for t=0

#pragma unroll 1
    for (int m = 0; m < NMACRO; ++m) {
        // ring shift + 3 new 'other' rows (consumed >=4 steps later)
#pragma unroll
        for (int j = 0; j < 12; ++j) oring[j] = oring[j + 3];
#pragma unroll
        for (int j = 0; j < 3; ++j) oring[12 + j] = loadOther(rBase + 3 * m + j);

#pragma unroll
        for (int p = 0; p < 3; ++p) {
            const int r = rBase + 3 * m + p;     // img row fed this step
            const float2 img = nextImg;
            nextImg = loadImg(r + 1);            // prefetch next step's row

            // ---------- Pass D: dilate stage k at row yd = r-k-2 (pre-update windows) ----------
#pragma unroll
            for (int k = 1; k <= 10; ++k) {
                const int yd = r - k - 2;
                if (yd >= y0 && yd < y0 + VROWS) {      // wave-uniform ownership guard
                    const float2 a = E[k][MOD3(p - k)];       // row yd-1
                    const float2 b = E[k][MOD3(p - k + 1)];   // row yd
                    const float2 c = E[k][MOD3(p - k + 2)];   // row yd+1
                    float2 vm;
                    if (yd == 0) {                // image top: exclude row -1
                        vm.x = vmax(b.x, c.x); vm.y = vmax(b.y, c.y);
                    } else if (yd == HH - 1) {    // image bottom: exclude row 1024
                        vm.x = vmax(a.x, b.x); vm.y = vmax(a.y, b.y);
                    } else {
                        vm.x = vmax3(a.x, b.x, c.x); vm.y = vmax3(a.y, b.y, c.y);
                    }
                    if (sEdge) { if (colOOB) vm = f2s(-INFINITY); }  // col truncation at image edge
                    const float vl = dpp_up1(vm.y);
                    const float vr = dpp_dn1(vm.x);
                    float2 h;
                    h.x = vmax3(vl,   vm.x, vm.y);
                    h.y = vmax3(vm.x, vm.y, vr);
                    const float2 io = E[k - 1][MOD3(p - k + 1)];  // img_k at row yd
                    float2 ct;
                    ct.x = relu(io.x - h.x);
                    ct.y = relu(io.y - h.y);
                    const float2 ot = oring[10 + p - k];
                    sumS.x += ct.x; sumS.y += ct.y;
                    sumP.x = fmaf(ot.x, ct.x, sumP.x);
                    sumP.y = fmaf(ot.y, ct.y, sumP.y);
                }
            }

            // ---------- Pass E: erode cascade, stage k emits row r-k ----------
            E[0][MOD3(p)] = img;
            float2 np_ = img;    // new row of stage k-1 (row r-k+1 when at stage k)
#pragma unroll
            for (int k = 1; k <= 10; ++k) {
                const float2 A = E[k - 1][MOD3(p - k + 2)];  // row r-k-1 (up)
                const float2 B = E[k - 1][MOD3(p - k)];      // row r-k   (center)
                const float2 C = np_;                        // row r-k+1 (down)
                const float bl = dpp_up1(B.y);
                const float br = dpp_dn1(B.x);
                float2 ne;
                ne.x = min5(A.x, C.x, bl,  B.y, B.x);
                ne.y = min5(A.y, C.y, B.x, br,  B.y);
                const int yN = r - k;
                if ((unsigned)yN >= HH) {        // out-of-image rows stay +inf
                    ne = f2s(INFINITY);
                } else if (sEdge) {
                    if (colOOB) ne = f2s(INFINITY);  // out-of-image cols stay +inf
                }
                E[k][MOD3(p - k)] = ne;
                np_ = ne;
            }
        }
    }

    // ---------- reduce: mask unowned lanes, wave-reduce, 2 atomics ----------
    if (!ownedLane) { sumS = f2s(0.f); sumP = f2s(0.f); }
    float aS = sumS.x + sumS.y;
    float aP = sumP.x + sumP.y;
#pragma unroll
    for (int off = 32; off > 0; off >>= 1) {
        aS += __shfl_down(aS, off, 64);
        aP += __shfl_down(aP, off, 64);
    }
    if (lane == 0) {
        const int base = plane * 4 + tensor * 2;
        atomicAdd(&sums[base],     aS);   // sum(skel)
        atomicAdd(&sums[base + 1], aP);   // sum(skel * other)
    }
}

__global__ void finalize_kernel(const float* __restrict__ s4, float* __restrict__ out)
{
    __shared__ float cl[32];
    int p = threadIdx.x;
    if (p < 32) {
        const float* s = s4 + p * 4;
        float tprec = s[1] / (s[0] + 1e-6f);
        float tsens = s[3] / (s[2] + 1e-6f);
        cl[p] = 2.f * tprec * tsens / (tprec + tsens + 1e-6f);
    }
    __syncthreads();
    if (p == 0) {
        float a = 0.f, vch = 0.f;
        for (int b = 0; b < 16; ++b) { a += cl[b * 2]; vch += cl[b * 2 + 1]; }
        out[0] = 1.f - 0.5f * (a / 16.f + vch / 16.f);
    }
}

extern "C" void kernel_launch(void* const* d_in, const int* in_sizes, int n_in,
                              void* d_out, int out_size, void* d_ws, size_t ws_size,
                              hipStream_t stream)
{
    const float* logits  = (const float*)d_in[0];
    const float* targets = (const float*)d_in[1];
    float* out  = (float*)d_out;
    float* sums = (float*)d_ws;

    hipMemsetAsync(d_ws, 0, 32 * 4 * sizeof(float), stream);

    // 5120 waves = 10 col-strips x 8 row-strips x 64 jobs; 4 waves per block
    skel_kernel<<<1280, 256, 0, stream>>>(logits, targets, sums);
    finalize_kernel<<<1, 64, 0, stream>>>(sums, out);
}